// Round 4
// baseline (5417.028 us; speedup 1.0000x reference)
//
#include <hip/hip_runtime.h>
#include <math.h>

#define BATCH   4
#define NPTS    16384
#define NGROUP  1024
#define GSIZE   32
#define ENCC    384
#define BN_EPS  1e-5f

// ============================ FPS ============================
// One block per batch, 1024 threads, 16 points/thread in registers (pure-VGPR
// inner loop). Mirrors the reference scan exactly: emit far, update min_d,
// argmax (first-index tie-break) -> next far. Direct (p-c)^2 distance form
// (matches reference FPS; KNN uses the expansion form like the reference).
// Single barrier per step: leaders write per-wave argmax to a double-buffered
// 16-slot scratch; every wave then redundantly reduces the 16 slots in-wave.
__global__ __launch_bounds__(1024, 1)
void fps_kernel(const float* __restrict__ xyz, float4* __restrict__ centers4) {
  const int b   = blockIdx.x;
  const int tid = threadIdx.x;
  const float* base = xyz + (size_t)b * NPTS * 3;

  float px[16], py[16], pz[16], md[16];
#pragma unroll
  for (int t = 0; t < 16; ++t) {
    int i = tid + (t << 10);
    px[t] = base[i * 3 + 0];
    py[t] = base[i * 3 + 1];
    pz[t] = base[i * 3 + 2];
    md[t] = 1e10f;
  }

  __shared__ float s_val[2][16];
  __shared__ int   s_idx[2][16];

  int far = 0;
  for (int s = 0; s < NGROUP; ++s) {
    // current center (uniform address -> broadcast load)
    float cx = base[far * 3 + 0];
    float cy = base[far * 3 + 1];
    float cz = base[far * 3 + 2];
    if (tid == 0) {
      centers4[(size_t)b * NGROUP + s] =
          make_float4(cx, cy, cz, cx * cx + cy * cy + cz * cz);
    }

    // update min-dist + inline argmax (ascending idx scan -> first-max kept)
    float bv = -1.0f;
    int   bi = 0;
#pragma unroll
    for (int t = 0; t < 16; ++t) {
      float dx = px[t] - cx, dy = py[t] - cy, dz = pz[t] - cz;
      float d  = dx * dx + dy * dy + dz * dz;
      md[t] = fminf(md[t], d);
      if (md[t] > bv) { bv = md[t]; bi = tid + (t << 10); }
    }
    // wave argmax (value desc, index asc tie-break)
#pragma unroll
    for (int off = 32; off > 0; off >>= 1) {
      float ov = __shfl_down(bv, off);
      int   oi = __shfl_down(bi, off);
      if (ov > bv || (ov == bv && oi < bi)) { bv = ov; bi = oi; }
    }
    const int buf = s & 1;
    if ((tid & 63) == 0) { s_val[buf][tid >> 6] = bv; s_idx[buf][tid >> 6] = bi; }
    __syncthreads();
    // every wave redundantly reduces the 16 per-wave winners (no 2nd barrier;
    // double buffer prevents next-step write/read races across waves)
    float v = s_val[buf][tid & 15];
    int   i = s_idx[buf][tid & 15];
#pragma unroll
    for (int off = 8; off > 0; off >>= 1) {
      float ov = __shfl_xor(v, off);
      int   oi = __shfl_xor(i, off);
      if (ov > v || (ov == v && oi < i)) { v = ov; i = oi; }
    }
    far = i;
  }
}

// ============================ KNN ============================
// One block per center (4096 blocks), 256 threads, 64 distances/thread in
// registers. d2 = c2 + x2 - 2*dot (reference expansion). 32 rounds of
// global-min extraction via per-thread chunk-min + owner rescan. Only the
// 32-NN SET matters downstream (encoder max-pools over k).
__global__ __launch_bounds__(256)
void knn_kernel(const float* __restrict__ xyz, const float4* __restrict__ centers4,
                float* __restrict__ neigh) {
  const int gi  = blockIdx.x;        // b*NGROUP + g
  const int b   = gi >> 10;
  const int tid = threadIdx.x;
  const float* base = xyz + (size_t)b * NPTS * 3;
  const float4 c4 = centers4[gi];

  float d[64];
  float cmv = 1e30f;
  int   cpos = 0;
#pragma unroll
  for (int t = 0; t < 64; ++t) {
    int i = tid + (t << 8);
    float x = base[i * 3 + 0], y = base[i * 3 + 1], z = base[i * 3 + 2];
    float x2  = x * x + y * y + z * z;
    float dt  = x * c4.x + y * c4.y + z * c4.z;
    float dd  = c4.w + x2 - 2.0f * dt;
    d[t] = dd;
    if (dd < cmv) { cmv = dd; cpos = t; }   // strict < keeps smallest t
  }

  __shared__ float s_cmv[256];
  __shared__ int   s_owner;
  __shared__ int   s_sel[GSIZE];
  s_cmv[tid] = cmv;
  __syncthreads();

  for (int r = 0; r < GSIZE; ++r) {
    if (tid < 64) {
      float v = s_cmv[tid]; int o = tid;
      float a = s_cmv[tid + 64];  if (a < v) { v = a; o = tid + 64; }
      float c = s_cmv[tid + 128]; if (c < v) { v = c; o = tid + 128; }
      float e = s_cmv[tid + 192]; if (e < v) { v = e; o = tid + 192; }
#pragma unroll
      for (int off = 32; off > 0; off >>= 1) {
        float ov = __shfl_down(v, off);
        int   oo = __shfl_down(o, off);
        if (ov < v || (ov == v && oo < o)) { v = ov; o = oo; }
      }
      if (tid == 0) s_owner = o;
    }
    __syncthreads();
    if (tid == s_owner) {
      s_sel[r] = tid + (cpos << 8);
#pragma unroll
      for (int t = 0; t < 64; ++t) if (t == cpos) d[t] = 1e30f;
      float nv = 1e30f; int np = 0;
#pragma unroll
      for (int t = 0; t < 64; ++t) { if (d[t] < nv) { nv = d[t]; np = t; } }
      cmv = nv; cpos = np;
      s_cmv[tid] = nv;
    }
    __syncthreads();
  }

  if (tid < GSIZE) {
    int i = s_sel[tid];
    float x = base[i * 3 + 0] - c4.x;
    float y = base[i * 3 + 1] - c4.y;
    float z = base[i * 3 + 2] - c4.z;
    size_t o = ((size_t)gi * GSIZE + tid) * 3;
    neigh[o + 0] = x; neigh[o + 1] = y; neigh[o + 2] = z;
  }
}

// ========================== Encoder ==========================
// One block per group, 256 threads. Static 64KB LDS -> 2 blocks/CU.
// Thread owns output channel(s); weight rows stream from L2 into registers
// (per-lane global loads); activation reads are wave-uniform LDS broadcasts
// (conflict-free). All restructures preserve per-output summation order
// (bitwise-identical to the dot-product form).
//
// Algebraic cut: h = [fg | f2] with fg point-independent ->
//   h@w3.T = (w3[:, :256] . fg)  [per-channel "base", computed once]
//          + (w3[:, 256:] . f2[p])
//
// LDS-broadcast diet (this round): phase C uses 4 channels x 8 points per
// thread (32 fma per broadcast pair, was 16); phase D fuses the split-K
// half-channel's activation reads with the full channel's (same addresses:
// cD*512 + kh*256 + jt_local*8 == cD*512 + jt*8). Uniform reads/wave:
// 9.2k -> 6.2k.
//
// LDS (floats): [ f2[32][256] : 8192 ][ AH region : 8192 ] = 16384 = 64KB
//   AH region time-multiplexes: r1[32][128] (A->B) + xs[32][4] / fg[256]
//   (post-B) -> a_half[16][512] (C/D passes) -> splitK scratch.
#define F2_OFF 0
#define AH_OFF 8192
#define R1_OFF 8192                   /* r1[32][128], live A->B */
#define XS_OFF 12288                  /* xs[32][4], live load->A */
#define FG_OFF 12288                  /* fg[256], live post-B->base (xs dead) */
#define SC_OFF 8192                   /* splitK scratch 128*17, inside AH */

__global__ __launch_bounds__(256, 2)
void encoder_kernel(const float* __restrict__ neigh,
                    const float* __restrict__ w1, const float* __restrict__ b1,
                    const float* __restrict__ g1, const float* __restrict__ be1,
                    const float* __restrict__ m1, const float* __restrict__ v1,
                    const float* __restrict__ w2, const float* __restrict__ b2,
                    const float* __restrict__ w3, const float* __restrict__ b3,
                    const float* __restrict__ g2, const float* __restrict__ be2,
                    const float* __restrict__ m2, const float* __restrict__ v2,
                    const float* __restrict__ w4, const float* __restrict__ b4,
                    float* __restrict__ out) {
  __shared__ float lds[16384];        // exactly 64KB
  const int gi  = blockIdx.x;
  const int tid = threadIdx.x;

  if (tid < GSIZE * 3) {
    int p = tid / 3, j = tid % 3;
    lds[XS_OFF + p * 4 + j] = neigh[(size_t)gi * (GSIZE * 3) + tid];
  }
  __syncthreads();

  // ---- phase A: r1[32][128] = relu(bn1(x@w1.T + b1)) ----
  {
    const int c  = tid & 127;
    const int ph = tid >> 7;
    float w10 = w1[c * 3 + 0], w11 = w1[c * 3 + 1], w12 = w1[c * 3 + 2];
    float b1c = b1[c], m1c = m1[c], be1c = be1[c];
    float s1c = g1[c] / sqrtf(v1[c] + BN_EPS);
#pragma unroll
    for (int i = 0; i < 16; ++i) {
      int p = i * 2 + ph;
      float x0 = lds[XS_OFF + p * 4 + 0];
      float x1 = lds[XS_OFF + p * 4 + 1];
      float x2 = lds[XS_OFF + p * 4 + 2];
      float val = x0 * w10 + x1 * w11 + x2 * w12 + b1c;
      val = (val - m1c) * s1c + be1c;
      val = fmaxf(val, 0.0f);
      lds[R1_OFF + p * 128 + c] = val;
    }
  }
  __syncthreads();

  // ---- phase B: f2[32][256] = r1@w2.T + b2 ; fg[c] = max_p f2[p][c] ----
  {
    const int c = tid;
    float acc[32];
#pragma unroll
    for (int p = 0; p < 32; ++p) acc[p] = 0.0f;
    const float* w2r = w2 + (size_t)c * 128;
    for (int jt = 0; jt < 16; ++jt) {
      float4 wA = *reinterpret_cast<const float4*>(w2r + jt * 8);
      float4 wB = *reinterpret_cast<const float4*>(w2r + jt * 8 + 4);
#pragma unroll
      for (int p = 0; p < 32; ++p) {
        const float4 rA = *reinterpret_cast<const float4*>(&lds[R1_OFF + p * 128 + jt * 8]);
        const float4 rB = *reinterpret_cast<const float4*>(&lds[R1_OFF + p * 128 + jt * 8 + 4]);
        acc[p] += rA.x * wA.x + rA.y * wA.y + rA.z * wA.z + rA.w * wA.w
                + rB.x * wB.x + rB.y * wB.y + rB.z * wB.z + rB.w * wB.w;
      }
    }
    float b2c = b2[c];
    float fg  = -1e30f;
#pragma unroll
    for (int p = 0; p < 32; ++p) { acc[p] += b2c; fg = fmaxf(fg, acc[p]); }
#pragma unroll
    for (int p = 0; p < 32; ++p) lds[F2_OFF + p * 256 + c] = acc[p];
    lds[FG_OFF + c] = fg;           // r1/xs dead; fg overlays xs slot
  }
  __syncthreads();

  // ---- phase C setup: 4 channels x 8 points per thread ----
  const int cb = tid & 127;          // channel base: channels cb + 128*j
  const int ph = tid >> 7;           // point-half selector (wave-uniform)
  float b3c[4], m2c[4], bec[4], scc[4], base[4];
#pragma unroll
  for (int j = 0; j < 4; ++j) {
    const int c = cb + 128 * j;
    b3c[j] = b3[c]; m2c[j] = m2[c]; bec[j] = be2[c];
    scc[j] = g2[c] / sqrtf(v2[c] + BN_EPS);
    base[j] = 0.0f;
  }
  // base dots: base[j] = w3[c][0:256] . fg  (once per channel; both ph
  // threads compute identically -> bitwise same a_half later)
  for (int jt = 0; jt < 32; ++jt) {
    const float4 f0 = *reinterpret_cast<const float4*>(&lds[FG_OFF + jt * 8]);
    const float4 f1 = *reinterpret_cast<const float4*>(&lds[FG_OFF + jt * 8 + 4]);
#pragma unroll
    for (int j = 0; j < 4; ++j) {
      const float* wr = w3 + (size_t)(cb + 128 * j) * 512 + jt * 8;
      float4 a0 = *reinterpret_cast<const float4*>(wr);
      float4 a1 = *reinterpret_cast<const float4*>(wr + 4);
      base[j] += f0.x * a0.x + f0.y * a0.y + f0.z * a0.z + f0.w * a0.w
               + f1.x * a1.x + f1.y * a1.y + f1.z * a1.z + f1.w * a1.w;
    }
  }
  __syncthreads();   // fg reads done before a_half overwrites AH region

  // phase D channel assignment (split-K balance for channels 256..383)
  const int cD = 256 + (tid & 127);
  const int kh = tid >> 7;                 // K-half 0/1 (wave-uniform)
  float ma = -1e30f, mb = -1e30f;

  // ---- two passes of 16 points: phase C (a_half) + phase D (max-accum) ----
  for (int pass = 0; pass < 2; ++pass) {
    // phase C: a_half[lp][c] = relu(bn2(base + w3[c][256:] . f2[p] + b3))
    // 4 channels x 8 points per thread; f2 reads stay wave-uniform (ph
    // uniform), each broadcast pair feeds 32 fma.
    {
      float acc[4][8];
#pragma unroll
      for (int j = 0; j < 4; ++j)
#pragma unroll
        for (int pp = 0; pp < 8; ++pp) acc[j][pp] = base[j];
      for (int jt = 0; jt < 32; ++jt) {
        float4 w0[4], w1r[4];
#pragma unroll
        for (int j = 0; j < 4; ++j) {
          const float* wr = w3 + (size_t)(cb + 128 * j) * 512 + 256 + jt * 8;
          w0[j]  = *reinterpret_cast<const float4*>(wr);
          w1r[j] = *reinterpret_cast<const float4*>(wr + 4);
        }
#pragma unroll
        for (int pp = 0; pp < 8; ++pp) {
          const int p = pass * 16 + ph * 8 + pp;
          const float4 f0 = *reinterpret_cast<const float4*>(&lds[F2_OFF + p * 256 + jt * 8]);
          const float4 f1 = *reinterpret_cast<const float4*>(&lds[F2_OFF + p * 256 + jt * 8 + 4]);
#pragma unroll
          for (int j = 0; j < 4; ++j) {
            acc[j][pp] += f0.x * w0[j].x + f0.y * w0[j].y + f0.z * w0[j].z + f0.w * w0[j].w
                        + f1.x * w1r[j].x + f1.y * w1r[j].y + f1.z * w1r[j].z + f1.w * w1r[j].w;
          }
        }
      }
#pragma unroll
      for (int pp = 0; pp < 8; ++pp) {
        const int lp = ph * 8 + pp;        // local point 0..15
#pragma unroll
        for (int j = 0; j < 4; ++j) {
          float v = ((acc[j][pp] + b3c[j]) - m2c[j]) * scc[j] + bec[j];
          lds[AH_OFF + lp * 512 + cb + 128 * j] = fmaxf(v, 0.0f);
        }
      }
    }
    __syncthreads();

    // phase D: accumulate max over this pass's 16 points.
    // Fused reads: full channel c0=tid over jt 0..63; half channel cD over
    // its kh jt-half shares the SAME h0/h1 reads (address identity).
    {
      float dA[16], dB[16];
#pragma unroll
      for (int pp = 0; pp < 16; ++pp) { dA[pp] = 0.0f; dB[pp] = 0.0f; }
      const float* w4r0 = w4 + (size_t)tid * 512;
      const float* w4r1 = w4 + (size_t)cD * 512;

#define D_CHUNK(JT0, WITH_B)                                                    \
      for (int jt = (JT0); jt < (JT0) + 32; ++jt) {                             \
        float4 a0 = *reinterpret_cast<const float4*>(w4r0 + jt * 8);            \
        float4 a1 = *reinterpret_cast<const float4*>(w4r0 + jt * 8 + 4);        \
        float4 q0 = make_float4(0.f, 0.f, 0.f, 0.f), q1 = q0;                   \
        if (WITH_B) {                                                           \
          q0 = *reinterpret_cast<const float4*>(w4r1 + jt * 8);                 \
          q1 = *reinterpret_cast<const float4*>(w4r1 + jt * 8 + 4);             \
        }                                                                       \
        _Pragma("unroll")                                                       \
        for (int pp = 0; pp < 16; ++pp) {                                       \
          const float4 h0 = *reinterpret_cast<const float4*>(&lds[AH_OFF + pp * 512 + jt * 8]);     \
          const float4 h1 = *reinterpret_cast<const float4*>(&lds[AH_OFF + pp * 512 + jt * 8 + 4]); \
          dA[pp] += h0.x * a0.x + h0.y * a0.y + h0.z * a0.z + h0.w * a0.w       \
                  + h1.x * a1.x + h1.y * a1.y + h1.z * a1.z + h1.w * a1.w;      \
          if (WITH_B)                                                           \
            dB[pp] += h0.x * q0.x + h0.y * q0.y + h0.z * q0.z + h0.w * q0.w     \
                    + h1.x * q1.x + h1.y * q1.y + h1.z * q1.z + h1.w * q1.w;    \
        }                                                                       \
      }

      if (kh == 0) { D_CHUNK(0, true)  D_CHUNK(32, false) }
      else         { D_CHUNK(0, false) D_CHUNK(32, true)  }
#undef D_CHUNK

#pragma unroll
      for (int pp = 0; pp < 16; ++pp) ma = fmaxf(ma, dA[pp]);

      __syncthreads();            // all a_half reads complete
      if (kh) {
#pragma unroll
        for (int pp = 0; pp < 16; ++pp)
          lds[SC_OFF + (tid - 128) * 17 + pp] = dB[pp];
      }
      __syncthreads();
      if (!kh) {
#pragma unroll
        for (int pp = 0; pp < 16; ++pp)
          mb = fmaxf(mb, dB[pp] + lds[SC_OFF + tid * 17 + pp]);
      }
      __syncthreads();            // scratch reads done before next pass C
    }
  }

  out[(size_t)gi * ENCC + tid] = ma + b4[tid];
  if (kh == 0) out[(size_t)gi * ENCC + cD] = mb + b4[cD];
}

// ========================== launcher ==========================
extern "C" void kernel_launch(void* const* d_in, const int* in_sizes, int n_in,
                              void* d_out, int out_size, void* d_ws, size_t ws_size,
                              hipStream_t stream) {
  const float* xyz = (const float*)d_in[0];
  const float* w1  = (const float*)d_in[1];
  const float* b1  = (const float*)d_in[2];
  const float* g1  = (const float*)d_in[3];
  const float* be1 = (const float*)d_in[4];
  const float* m1  = (const float*)d_in[5];
  const float* v1  = (const float*)d_in[6];
  const float* w2  = (const float*)d_in[7];
  const float* b2  = (const float*)d_in[8];
  const float* w3  = (const float*)d_in[9];
  const float* b3  = (const float*)d_in[10];
  const float* g2  = (const float*)d_in[11];
  const float* be2 = (const float*)d_in[12];
  const float* m2  = (const float*)d_in[13];
  const float* v2  = (const float*)d_in[14];
  const float* w4  = (const float*)d_in[15];
  const float* b4  = (const float*)d_in[16];
  float* out = (float*)d_out;

  // workspace layout
  float4* centers4 = (float4*)d_ws;                                    // 64 KB
  float*  neigh    = (float*)((char*)d_ws + (size_t)BATCH * NGROUP * sizeof(float4)); // 1.5 MB

  fps_kernel<<<BATCH, 1024, 0, stream>>>(xyz, centers4);
  knn_kernel<<<BATCH * NGROUP, 256, 0, stream>>>(xyz, centers4, neigh);
  encoder_kernel<<<BATCH * NGROUP, 256, 0, stream>>>(
      neigh, w1, b1, g1, be1, m1, v1, w2, b2, w3, b3, g2, be2, m2, v2, w4, b4, out);
}

// Round 5
// 2528.605 us; speedup vs baseline: 2.1423x; 2.1423x over previous
//
#include <hip/hip_runtime.h>
#include <math.h>

#define BATCH   4
#define NPTS    16384
#define NGROUP  1024
#define GSIZE   32
#define ENCC    384
#define BN_EPS  1e-5f

typedef __bf16 bf16x8 __attribute__((ext_vector_type(8)));
typedef float  f32x4  __attribute__((ext_vector_type(4)));

// DPP cross-lane argmax/argmin (VALU pipe, ~10cyc/step vs ~120 for ds_bpermute).
// row_ror 8/4/2/1 = full 16-lane-row butterfly; row_bcast15+31 fold rows so
// lanes 48-63 hold the wave64 result. Combine is exact selection -> bitwise
// identical to the shfl version. bound_ctrl=false + old=src => unwritten
// lanes combine with self (idempotent, safe for max/min).
#define DPP_AMAX(V, I, CTRL)                                                   \
  { int _vb = __float_as_int(V);                                               \
    int _ov = __builtin_amdgcn_update_dpp(_vb, _vb, (CTRL), 0xf, 0xf, false);  \
    int _oi = __builtin_amdgcn_update_dpp((I), (I), (CTRL), 0xf, 0xf, false);  \
    float _of = __int_as_float(_ov);                                           \
    if (_of > (V) || (_of == (V) && _oi < (I))) { (V) = _of; (I) = _oi; } }

#define DPP_AMIN(V, I, CTRL)                                                   \
  { int _vb = __float_as_int(V);                                               \
    int _ov = __builtin_amdgcn_update_dpp(_vb, _vb, (CTRL), 0xf, 0xf, false);  \
    int _oi = __builtin_amdgcn_update_dpp((I), (I), (CTRL), 0xf, 0xf, false);  \
    float _of = __int_as_float(_ov);                                           \
    if (_of < (V) || (_of == (V) && _oi < (I))) { (V) = _of; (I) = _oi; } }

// ============================ FPS ============================
// One block per batch, 1024 threads, 16 pts/thread in registers. Exact
// reference scan (direct (p-c)^2, first-index tiebreak). Reduction via DPP:
// wave64 argmax (6 DPP steps) -> lane63 writes per-wave winner -> barrier ->
// each lane reads slot (tid&15) -> 4-step DPP row butterfly -> all lanes
// hold the global argmax. One barrier per step, ~0 bpermutes.
__global__ __launch_bounds__(1024, 1)
void fps_kernel(const float* __restrict__ xyz, float4* __restrict__ centers4) {
  const int b   = blockIdx.x;
  const int tid = threadIdx.x;
  const float* base = xyz + (size_t)b * NPTS * 3;

  float px[16], py[16], pz[16], md[16];
#pragma unroll
  for (int t = 0; t < 16; ++t) {
    int i = tid + (t << 10);
    px[t] = base[i * 3 + 0];
    py[t] = base[i * 3 + 1];
    pz[t] = base[i * 3 + 2];
    md[t] = 1e10f;
  }

  __shared__ float s_val[2][16];
  __shared__ int   s_idx[2][16];

  int far = 0;
  for (int s = 0; s < NGROUP; ++s) {
    float cx = base[far * 3 + 0];
    float cy = base[far * 3 + 1];
    float cz = base[far * 3 + 2];
    if (tid == 0) {
      centers4[(size_t)b * NGROUP + s] =
          make_float4(cx, cy, cz, cx * cx + cy * cy + cz * cz);
    }

    float bv = -1.0f;
    int   bi = 0;
#pragma unroll
    for (int t = 0; t < 16; ++t) {
      float dx = px[t] - cx, dy = py[t] - cy, dz = pz[t] - cz;
      float d  = dx * dx + dy * dy + dz * dz;
      md[t] = fminf(md[t], d);
      if (md[t] > bv) { bv = md[t]; bi = tid + (t << 10); }  // > keeps first
    }
    // wave64 argmax via DPP (result valid in lanes 48-63)
    DPP_AMAX(bv, bi, 0x128)  // row_ror:8
    DPP_AMAX(bv, bi, 0x124)  // row_ror:4
    DPP_AMAX(bv, bi, 0x122)  // row_ror:2
    DPP_AMAX(bv, bi, 0x121)  // row_ror:1
    DPP_AMAX(bv, bi, 0x142)  // row_bcast:15
    DPP_AMAX(bv, bi, 0x143)  // row_bcast:31
    const int buf = s & 1;
    if ((tid & 63) == 63) { s_val[buf][tid >> 6] = bv; s_idx[buf][tid >> 6] = bi; }
    __syncthreads();
    // final 16-slot reduce: lane l holds slot l&15; row butterfly -> all lanes
    float v = s_val[buf][tid & 15];
    int  ii = s_idx[buf][tid & 15];
    DPP_AMAX(v, ii, 0x128)
    DPP_AMAX(v, ii, 0x124)
    DPP_AMAX(v, ii, 0x122)
    DPP_AMAX(v, ii, 0x121)
    far = ii;
  }
}

// ============================ KNN ============================
// One block per center, 256 threads, 64 distances/thread in registers.
// d2 = c2 + x2 - 2*dot (reference expansion). 32 extraction rounds; the
// 64-lane min-reduce now uses DPP instead of a shfl chain.
__global__ __launch_bounds__(256)
void knn_kernel(const float* __restrict__ xyz, const float4* __restrict__ centers4,
                float* __restrict__ neigh) {
  const int gi  = blockIdx.x;
  const int b   = gi >> 10;
  const int tid = threadIdx.x;
  const float* base = xyz + (size_t)b * NPTS * 3;
  const float4 c4 = centers4[gi];

  float d[64];
  float cmv = 1e30f;
  int   cpos = 0;
#pragma unroll
  for (int t = 0; t < 64; ++t) {
    int i = tid + (t << 8);
    float x = base[i * 3 + 0], y = base[i * 3 + 1], z = base[i * 3 + 2];
    float x2  = x * x + y * y + z * z;
    float dt  = x * c4.x + y * c4.y + z * c4.z;
    float dd  = c4.w + x2 - 2.0f * dt;
    d[t] = dd;
    if (dd < cmv) { cmv = dd; cpos = t; }
  }

  __shared__ float s_cmv[256];
  __shared__ int   s_owner;
  __shared__ int   s_sel[GSIZE];
  s_cmv[tid] = cmv;
  __syncthreads();

  for (int r = 0; r < GSIZE; ++r) {
    if (tid < 64) {
      float v = s_cmv[tid]; int o = tid;
      float a = s_cmv[tid + 64];  if (a < v) { v = a; o = tid + 64; }
      float c = s_cmv[tid + 128]; if (c < v) { v = c; o = tid + 128; }
      float e = s_cmv[tid + 192]; if (e < v) { v = e; o = tid + 192; }
      DPP_AMIN(v, o, 0x128)
      DPP_AMIN(v, o, 0x124)
      DPP_AMIN(v, o, 0x122)
      DPP_AMIN(v, o, 0x121)
      DPP_AMIN(v, o, 0x142)
      DPP_AMIN(v, o, 0x143)
      if (tid == 63) s_owner = o;
    }
    __syncthreads();
    if (tid == s_owner) {
      s_sel[r] = tid + (cpos << 8);
#pragma unroll
      for (int t = 0; t < 64; ++t) if (t == cpos) d[t] = 1e30f;
      float nv = 1e30f; int np = 0;
#pragma unroll
      for (int t = 0; t < 64; ++t) { if (d[t] < nv) { nv = d[t]; np = t; } }
      cmv = nv; cpos = np;
      s_cmv[tid] = nv;
    }
    __syncthreads();
  }

  if (tid < GSIZE) {
    int i = s_sel[tid];
    float x = base[i * 3 + 0] - c4.x;
    float y = base[i * 3 + 1] - c4.y;
    float z = base[i * 3 + 2] - c4.z;
    size_t o = ((size_t)gi * GSIZE + tid) * 3;
    neigh[o + 0] = x; neigh[o + 1] = y; neigh[o + 2] = z;
  }
}

// ====================== weight prep (bf16 B-fragments) ======================
// Converts w2/w3/w4 to bf16 in exact MFMA B-fragment lane order:
//   dst[(nt*KS + ks)*64 + lane][8] = W[nt*16 + (lane&15)][ks*32 + (lane>>4)*8 + j]
// so encoder B-loads are coalesced 16B/lane and L2-hot across all 4096 blocks.
__global__ __launch_bounds__(256)
void prep_kernel(const float* __restrict__ w2f, const float* __restrict__ w3f,
                 const float* __restrict__ w4f, __bf16* __restrict__ bw2,
                 __bf16* __restrict__ bw3, __bf16* __restrict__ bw4) {
  int t = blockIdx.x * 256 + threadIdx.x;   // 61440 total
  const float* src; __bf16* dst; int K, local;
  if (t < 4096)       { src = w2f; dst = bw2; K = 128; local = t; }
  else if (t < 36864) { src = w3f; dst = bw3; K = 512; local = t - 4096; }
  else                { src = w4f; dst = bw4; K = 512; local = t - 36864; }
  int lane = local & 63, ntks = local >> 6;
  int KS = K >> 5;
  int ks = ntks & (KS - 1), nt = ntks / KS;
  int ch = nt * 16 + (lane & 15);
  int k0 = ks * 32 + (lane >> 4) * 8;
  const float* s = src + (size_t)ch * K + k0;
  bf16x8 v;
#pragma unroll
  for (int j = 0; j < 8; ++j) v[j] = (__bf16)s[j];
  *reinterpret_cast<bf16x8*>(dst + (size_t)local * 8) = v;
}

// ========================== Encoder (MFMA bf16) ==========================
// One block per group, 256 thr = 4 waves. M = 32 pts (2 tiles), N = channels
// partitioned across waves, fp32 MFMA accumulators, fp32 BN/bias/max
// epilogues. Activations in LDS bf16 (strides 136/520: 16B-aligned, <=2-way
// bank aliasing). 48.7KB LDS -> 3 blocks/CU.
// Lane roles (16x16x32): lrow=lane&15 (A-row / B&D-col), lkg=lane>>4;
// A[lrow][lkg*8+j], B[lkg*8+j][lrow], D row=(lkg*4+j), col=lrow.
#define R1S 136
#define HSS 520

__global__ __launch_bounds__(256, 2)
void encoder_kernel(const float* __restrict__ neigh,
                    const float* __restrict__ w1, const float* __restrict__ b1,
                    const float* __restrict__ g1, const float* __restrict__ be1,
                    const float* __restrict__ m1, const float* __restrict__ v1,
                    const __bf16* __restrict__ bw2, const float* __restrict__ b2,
                    const __bf16* __restrict__ bw3, const float* __restrict__ b3,
                    const float* __restrict__ g2, const float* __restrict__ be2,
                    const float* __restrict__ m2, const float* __restrict__ v2,
                    const __bf16* __restrict__ bw4, const float* __restrict__ b4,
                    float* __restrict__ out) {
  __shared__ __bf16 r1s[32][R1S];     // 8704 B   (relu-bn1 activations)
  __shared__ __bf16 hs[32][HSS];      // 33280 B  (h = [fg|f2], then a)
  __shared__ float  xs[32][4];        // 512 B
  __shared__ float  scr[4][388];      // 6208 B   (phase D partial maxes)

  const int gi = blockIdx.x, tid = threadIdx.x;
  const int w = tid >> 6, lane = tid & 63;
  const int lrow = lane & 15, lkg = lane >> 4;

  if (tid < GSIZE * 3) {
    int p = tid / 3, j = tid % 3;
    xs[p][j] = neigh[(size_t)gi * (GSIZE * 3) + tid];
  }
  __syncthreads();

  // ---- phase A (VALU fp32): r1 = relu(bn1(x@w1.T + b1)) -> bf16 LDS ----
  {
    const int c = tid & 127, ph2 = tid >> 7;
    float w10 = w1[c * 3 + 0], w11 = w1[c * 3 + 1], w12 = w1[c * 3 + 2];
    float b1c = b1[c], m1c = m1[c], be1c = be1[c];
    float s1c = g1[c] / sqrtf(v1[c] + BN_EPS);
#pragma unroll
    for (int i = 0; i < 16; ++i) {
      int p = i * 2 + ph2;
      float val = xs[p][0] * w10 + xs[p][1] * w11 + xs[p][2] * w12 + b1c;
      val = (val - m1c) * s1c + be1c;
      r1s[p][c] = (__bf16)fmaxf(val, 0.0f);
    }
  }
  __syncthreads();

  // ---- phase B (MFMA): f2[32][256] = r1@w2.T + b2 -> hs[:,256:512] ----
  {
    bf16x8 afr[2][4];
#pragma unroll
    for (int mt = 0; mt < 2; ++mt)
#pragma unroll
      for (int ks = 0; ks < 4; ++ks)
        afr[mt][ks] = *reinterpret_cast<const bf16x8*>(&r1s[mt * 16 + lrow][ks * 32 + lkg * 8]);
#pragma unroll
    for (int t = 0; t < 4; ++t) {
      const int nt = w * 4 + t;
      f32x4 acc0 = {0.f, 0.f, 0.f, 0.f}, acc1 = {0.f, 0.f, 0.f, 0.f};
#pragma unroll
      for (int ks = 0; ks < 4; ++ks) {
        bf16x8 bfr = *reinterpret_cast<const bf16x8*>(bw2 + ((size_t)(nt * 4 + ks) * 64 + lane) * 8);
        acc0 = __builtin_amdgcn_mfma_f32_16x16x32_bf16(afr[0][ks], bfr, acc0, 0, 0, 0);
        acc1 = __builtin_amdgcn_mfma_f32_16x16x32_bf16(afr[1][ks], bfr, acc1, 0, 0, 0);
      }
      const int ch = nt * 16 + lrow;
      const float b2c = b2[ch];
#pragma unroll
      for (int j = 0; j < 4; ++j) {
        hs[lkg * 4 + j][256 + ch]      = (__bf16)(acc0[j] + b2c);
        hs[16 + lkg * 4 + j][256 + ch] = (__bf16)(acc1[j] + b2c);
      }
    }
  }
  __syncthreads();

  // ---- fg: per-channel max over 32 pts, replicated into hs[:,0:256] ----
  {
    float m = -1e30f;
#pragma unroll
    for (int p = 0; p < 32; ++p) m = fmaxf(m, (float)hs[p][256 + tid]);
    __bf16 mb = (__bf16)m;
#pragma unroll
    for (int p = 0; p < 32; ++p) hs[p][tid] = mb;
  }
  __syncthreads();

  // ---- phase C (MFMA): a = relu(bn2(h@w3.T + b3)), in-place into hs ----
  {
    f32x4 acc[8][2];
#pragma unroll
    for (int u = 0; u < 8; ++u) { acc[u][0] = {0.f,0.f,0.f,0.f}; acc[u][1] = {0.f,0.f,0.f,0.f}; }
#pragma unroll
    for (int chunk = 0; chunk < 2; ++chunk) {
      for (int ks = 0; ks < 16; ++ks) {
        bf16x8 a0 = *reinterpret_cast<const bf16x8*>(&hs[lrow][ks * 32 + lkg * 8]);
        bf16x8 a1 = *reinterpret_cast<const bf16x8*>(&hs[16 + lrow][ks * 32 + lkg * 8]);
#pragma unroll
        for (int t = 0; t < 4; ++t) {
          const int u = chunk * 4 + t;
          const int nt = w * 8 + u;
          bf16x8 bfr = *reinterpret_cast<const bf16x8*>(bw3 + ((size_t)(nt * 16 + ks) * 64 + lane) * 8);
          acc[u][0] = __builtin_amdgcn_mfma_f32_16x16x32_bf16(a0, bfr, acc[u][0], 0, 0, 0);
          acc[u][1] = __builtin_amdgcn_mfma_f32_16x16x32_bf16(a1, bfr, acc[u][1], 0, 0, 0);
        }
      }
    }
    __syncthreads();   // all waves done reading h before overwrite with a
#pragma unroll
    for (int u = 0; u < 8; ++u) {
      const int ch = (w * 8 + u) * 16 + lrow;
      const float sc = g2[ch] / sqrtf(v2[ch] + BN_EPS);
      const float mm = m2[ch], bb = be2[ch], b3c = b3[ch];
#pragma unroll
      for (int mt = 0; mt < 2; ++mt)
#pragma unroll
        for (int j = 0; j < 4; ++j) {
          float val = ((acc[u][mt][j] + b3c) - mm) * sc + bb;
          hs[mt * 16 + lkg * 4 + j][ch] = (__bf16)fmaxf(val, 0.0f);
        }
    }
  }
  __syncthreads();

  // ---- phase D (MFMA): out[ch] = max_p(a@w4.T) + b4 ----
  {
    f32x4 acc[6][2];
#pragma unroll
    for (int u = 0; u < 6; ++u) { acc[u][0] = {0.f,0.f,0.f,0.f}; acc[u][1] = {0.f,0.f,0.f,0.f}; }
#pragma unroll
    for (int chunk = 0; chunk < 2; ++chunk) {
      for (int ks = 0; ks < 16; ++ks) {
        bf16x8 a0 = *reinterpret_cast<const bf16x8*>(&hs[lrow][ks * 32 + lkg * 8]);
        bf16x8 a1 = *reinterpret_cast<const bf16x8*>(&hs[16 + lrow][ks * 32 + lkg * 8]);
#pragma unroll
        for (int t = 0; t < 3; ++t) {
          const int u = chunk * 3 + t;
          const int nt = w * 6 + u;
          bf16x8 bfr = *reinterpret_cast<const bf16x8*>(bw4 + ((size_t)(nt * 16 + ks) * 64 + lane) * 8);
          acc[u][0] = __builtin_amdgcn_mfma_f32_16x16x32_bf16(a0, bfr, acc[u][0], 0, 0, 0);
          acc[u][1] = __builtin_amdgcn_mfma_f32_16x16x32_bf16(a1, bfr, acc[u][1], 0, 0, 0);
        }
      }
    }
#pragma unroll
    for (int u = 0; u < 6; ++u) {
      const int ch = (w * 6 + u) * 16 + lrow;
      float pm = -1e30f;
#pragma unroll
      for (int mt = 0; mt < 2; ++mt)
#pragma unroll
        for (int j = 0; j < 4; ++j) pm = fmaxf(pm, acc[u][mt][j]);
      scr[lkg][ch] = pm;   // partial over this lane's 8 points
    }
  }
  __syncthreads();

  {
    float r = fmaxf(fmaxf(scr[0][tid], scr[1][tid]), fmaxf(scr[2][tid], scr[3][tid]));
    out[(size_t)gi * ENCC + tid] = r + b4[tid];
    if (tid < 128) {
      int c2 = tid + 256;
      float r2 = fmaxf(fmaxf(scr[0][c2], scr[1][c2]), fmaxf(scr[2][c2], scr[3][c2]));
      out[(size_t)gi * ENCC + c2] = r2 + b4[c2];
    }
  }
}

// ========================== launcher ==========================
extern "C" void kernel_launch(void* const* d_in, const int* in_sizes, int n_in,
                              void* d_out, int out_size, void* d_ws, size_t ws_size,
                              hipStream_t stream) {
  const float* xyz = (const float*)d_in[0];
  const float* w1  = (const float*)d_in[1];
  const float* b1  = (const float*)d_in[2];
  const float* g1  = (const float*)d_in[3];
  const float* be1 = (const float*)d_in[4];
  const float* m1  = (const float*)d_in[5];
  const float* v1  = (const float*)d_in[6];
  const float* w2  = (const float*)d_in[7];
  const float* b2  = (const float*)d_in[8];
  const float* w3  = (const float*)d_in[9];
  const float* b3  = (const float*)d_in[10];
  const float* g2  = (const float*)d_in[11];
  const float* be2 = (const float*)d_in[12];
  const float* m2  = (const float*)d_in[13];
  const float* v2  = (const float*)d_in[14];
  const float* w4  = (const float*)d_in[15];
  const float* b4  = (const float*)d_in[16];
  float* out = (float*)d_out;

  // workspace layout (bytes): centers4 64K | neigh 1.5M | bw2 64K | bw3 512K | bw4 384K
  char* ws = (char*)d_ws;
  float4* centers4 = (float4*)ws;
  float*  neigh    = (float*)(ws + 65536);
  __bf16* bw2      = (__bf16*)(ws + 65536 + 1572864);
  __bf16* bw3      = (__bf16*)(ws + 65536 + 1572864 + 65536);
  __bf16* bw4      = (__bf16*)(ws + 65536 + 1572864 + 65536 + 524288);

  prep_kernel<<<240, 256, 0, stream>>>(w2, w3, w4, bw2, bw3, bw4);
  fps_kernel<<<BATCH, 1024, 0, stream>>>(xyz, centers4);
  knn_kernel<<<BATCH * NGROUP, 256, 0, stream>>>(xyz, centers4, neigh);
  encoder_kernel<<<BATCH * NGROUP, 256, 0, stream>>>(
      neigh, w1, b1, g1, be1, m1, v1, bw2, b2, bw3, b3, g2, be2, m2, v2, bw4, b4, out);
}

// Round 7
// 2111.781 us; speedup vs baseline: 2.5651x; 1.1974x over previous
//
#include <hip/hip_runtime.h>
#include <math.h>

#define BATCH   4
#define NPTS    16384
#define NGROUP  1024
#define GSIZE   32
#define ENCC    384
#define BN_EPS  1e-5f

typedef __bf16 bf16x8 __attribute__((ext_vector_type(8)));
typedef float  f32x4  __attribute__((ext_vector_type(4)));
typedef float  f32x2  __attribute__((ext_vector_type(2)));

// Packed fp32 VALU (CDNA2+): one instruction = 2 fp32 lanes. Bitwise identical
// per-half to the scalar ops (a + (-b) == a - b; same mul/fma ordering).
#define PK_ADD(d, a, b) asm("v_pk_add_f32 %0, %1, %2" : "=v"(d) : "v"(a), "v"(b));
#define PK_MUL(d, a, b) asm("v_pk_mul_f32 %0, %1, %2" : "=v"(d) : "v"(a), "v"(b));
#define PK_FMA(d, a, b, c) asm("v_pk_fma_f32 %0, %1, %2, %3" : "=v"(d) : "v"(a), "v"(b), "v"(c));

// DPP cross-lane reduce steps (validated in round 4/5: passed bitwise).
// row_ror 8/4/2/1 -> all 16 lanes of a row hold row-reduce; bcast15+31 fold
// rows so lanes 48-63 hold the wave64 result. old=src + bound_ctrl=false =>
// unwritten lanes combine with self (idempotent for max/min).
#define DPP_FMAX(V, CTRL)                                                      \
  { int _vb = __float_as_int(V);                                               \
    int _ov = __builtin_amdgcn_update_dpp(_vb, _vb, (CTRL), 0xf, 0xf, false);  \
    (V) = fmaxf((V), __int_as_float(_ov)); }

#define DPP_IMIN(V, CTRL)                                                      \
  { int _ov = __builtin_amdgcn_update_dpp((V), (V), (CTRL), 0xf, 0xf, false);  \
    (V) = min((V), _ov); }

#define DPP_AMIN(V, I, CTRL)                                                   \
  { int _vb = __float_as_int(V);                                               \
    int _ov = __builtin_amdgcn_update_dpp(_vb, _vb, (CTRL), 0xf, 0xf, false);  \
    int _oi = __builtin_amdgcn_update_dpp((I), (I), (CTRL), 0xf, 0xf, false);  \
    float _of = __int_as_float(_ov);                                           \
    if (_of < (V) || (_of == (V) && _oi < (I))) { (V) = _of; (I) = _oi; } }

// ============================ FPS ============================
// One block per batch, 512 threads x 32 consecutive points/thread, coords +
// min-dist held as f32x2 pairs (pure-VGPR inner loop, pk-math: 10 inst per
// 2 points). Selection is two-phase and exact: (1) value-only DPP max reduce
// across waves; (2) index recovery (min global index among md == gmax) scanned
// only by waves whose max matches. Matches jnp.argmax first-index semantics.
__global__ __launch_bounds__(512, 1)
void fps_kernel(const float* __restrict__ xyz, float4* __restrict__ centers4) {
  const int b   = blockIdx.x;
  const int tid = threadIdx.x;
  const float* base = xyz + (size_t)b * NPTS * 3;

  // load 32 consecutive points (96 floats = 24 float4), deinterleave to pairs
  f32x2 X[16], Y[16], Z[16], M[16];
  {
    float bufv[96];
    const float4* src = reinterpret_cast<const float4*>(base + (size_t)tid * 96);
#pragma unroll
    for (int q = 0; q < 24; ++q) {
      float4 v = src[q];
      bufv[q * 4 + 0] = v.x; bufv[q * 4 + 1] = v.y;
      bufv[q * 4 + 2] = v.z; bufv[q * 4 + 3] = v.w;
    }
#pragma unroll
    for (int j = 0; j < 16; ++j) {
      X[j] = f32x2{bufv[6 * j + 0], bufv[6 * j + 3]};
      Y[j] = f32x2{bufv[6 * j + 1], bufv[6 * j + 4]};
      Z[j] = f32x2{bufv[6 * j + 2], bufv[6 * j + 5]};
      M[j] = f32x2{1e10f, 1e10f};
    }
  }

  __shared__ float s_v[8];
  __shared__ int   s_i[8];

  int far = 0;
  for (int s = 0; s < NGROUP; ++s) {
    const float cx = base[far * 3 + 0];
    const float cy = base[far * 3 + 1];
    const float cz = base[far * 3 + 2];
    if (tid == 0) {
      centers4[(size_t)b * NGROUP + s] =
          make_float4(cx, cy, cz, cx * cx + cy * cy + cz * cz);
    }
    const f32x2 nx = {-cx, -cx}, ny = {-cy, -cy}, nz = {-cz, -cz};

    f32x2 bv2 = {-1.0f, -1.0f};
#pragma unroll
    for (int j = 0; j < 16; ++j) {
      f32x2 dx, dy, dz, dd;
      PK_ADD(dx, X[j], nx)
      PK_ADD(dy, Y[j], ny)
      PK_ADD(dz, Z[j], nz)
      PK_MUL(dd, dx, dx)
      PK_FMA(dd, dy, dy, dd)
      PK_FMA(dd, dz, dz, dd)
      M[j].x = fminf(M[j].x, dd.x);
      M[j].y = fminf(M[j].y, dd.y);
      bv2.x = fmaxf(bv2.x, M[j].x);
      bv2.y = fmaxf(bv2.y, M[j].y);
    }

    // phase 1: global max value
    float bv = fmaxf(bv2.x, bv2.y);
    DPP_FMAX(bv, 0x128) DPP_FMAX(bv, 0x124) DPP_FMAX(bv, 0x122)
    DPP_FMAX(bv, 0x121) DPP_FMAX(bv, 0x142) DPP_FMAX(bv, 0x143)
    if ((tid & 63) == 63) s_v[tid >> 6] = bv;
    __syncthreads();
    float gv = s_v[tid & 7];
    DPP_FMAX(gv, 0x124) DPP_FMAX(gv, 0x122) DPP_FMAX(gv, 0x121)  // all lanes

    // phase 2: first (smallest) global index achieving gv
    const float wm = __int_as_float(__builtin_amdgcn_readlane(__float_as_int(bv), 63));
    int cand = 0x7fffffff;
    if (wm == gv) {                       // wave-uniform predicate
#pragma unroll
      for (int j = 0; j < 16; ++j) {
        if (M[j].x == gv) cand = min(cand, (tid << 5) + 2 * j);
        if (M[j].y == gv) cand = min(cand, (tid << 5) + 2 * j + 1);
      }
    }
    DPP_IMIN(cand, 0x128) DPP_IMIN(cand, 0x124) DPP_IMIN(cand, 0x122)
    DPP_IMIN(cand, 0x121) DPP_IMIN(cand, 0x142) DPP_IMIN(cand, 0x143)
    if ((tid & 63) == 63) s_i[tid >> 6] = cand;
    __syncthreads();
    int gidx = s_i[tid & 7];
    DPP_IMIN(gidx, 0x124) DPP_IMIN(gidx, 0x122) DPP_IMIN(gidx, 0x121)
    far = gidx;
  }
}

// ============================ KNN ============================
// One block per center, 256 threads, 64 distances/thread in registers.
// d2 = c2 + x2 - 2*dot (reference expansion). 32 extraction rounds with
// DPP min-reduce. Only the 32-NN SET matters downstream (max-pool over k).
__global__ __launch_bounds__(256)
void knn_kernel(const float* __restrict__ xyz, const float4* __restrict__ centers4,
                float* __restrict__ neigh) {
  const int gi  = blockIdx.x;
  const int b   = gi >> 10;
  const int tid = threadIdx.x;
  const float* base = xyz + (size_t)b * NPTS * 3;
  const float4 c4 = centers4[gi];

  float d[64];
  float cmv = 1e30f;
  int   cpos = 0;
#pragma unroll
  for (int t = 0; t < 64; ++t) {
    int i = tid + (t << 8);
    float x = base[i * 3 + 0], y = base[i * 3 + 1], z = base[i * 3 + 2];
    float x2  = x * x + y * y + z * z;
    float dt  = x * c4.x + y * c4.y + z * c4.z;
    float dd  = c4.w + x2 - 2.0f * dt;
    d[t] = dd;
    if (dd < cmv) { cmv = dd; cpos = t; }
  }

  __shared__ float s_cmv[256];
  __shared__ int   s_owner;
  __shared__ int   s_sel[GSIZE];
  s_cmv[tid] = cmv;
  __syncthreads();

  for (int r = 0; r < GSIZE; ++r) {
    if (tid < 64) {
      float v = s_cmv[tid]; int o = tid;
      float a = s_cmv[tid + 64];  if (a < v) { v = a; o = tid + 64; }
      float c = s_cmv[tid + 128]; if (c < v) { v = c; o = tid + 128; }
      float e = s_cmv[tid + 192]; if (e < v) { v = e; o = tid + 192; }
      DPP_AMIN(v, o, 0x128)
      DPP_AMIN(v, o, 0x124)
      DPP_AMIN(v, o, 0x122)
      DPP_AMIN(v, o, 0x121)
      DPP_AMIN(v, o, 0x142)
      DPP_AMIN(v, o, 0x143)
      if (tid == 63) s_owner = o;
    }
    __syncthreads();
    if (tid == s_owner) {
      s_sel[r] = tid + (cpos << 8);
#pragma unroll
      for (int t = 0; t < 64; ++t) if (t == cpos) d[t] = 1e30f;
      float nv = 1e30f; int np = 0;
#pragma unroll
      for (int t = 0; t < 64; ++t) { if (d[t] < nv) { nv = d[t]; np = t; } }
      cmv = nv; cpos = np;
      s_cmv[tid] = nv;
    }
    __syncthreads();
  }

  if (tid < GSIZE) {
    int i = s_sel[tid];
    float x = base[i * 3 + 0] - c4.x;
    float y = base[i * 3 + 1] - c4.y;
    float z = base[i * 3 + 2] - c4.z;
    size_t o = ((size_t)gi * GSIZE + tid) * 3;
    neigh[o + 0] = x; neigh[o + 1] = y; neigh[o + 2] = z;
  }
}

// ====================== weight prep (bf16 B-fragments) ======================
// Converts w2/w3/w4 to bf16 in exact MFMA B-fragment lane order:
//   dst[(nt*KS + ks)*64 + lane][8] = W[nt*16 + (lane&15)][ks*32 + (lane>>4)*8 + j]
// so encoder B-loads are coalesced 16B/lane and L2-hot across all 4096 blocks.
__global__ __launch_bounds__(256)
void prep_kernel(const float* __restrict__ w2f, const float* __restrict__ w3f,
                 const float* __restrict__ w4f, __bf16* __restrict__ bw2,
                 __bf16* __restrict__ bw3, __bf16* __restrict__ bw4) {
  int t = blockIdx.x * 256 + threadIdx.x;   // 61440 total
  const float* src; __bf16* dst; int K, local;
  if (t < 4096)       { src = w2f; dst = bw2; K = 128; local = t; }
  else if (t < 36864) { src = w3f; dst = bw3; K = 512; local = t - 4096; }
  else                { src = w4f; dst = bw4; K = 512; local = t - 36864; }
  int lane = local & 63, ntks = local >> 6;
  int KS = K >> 5;
  int ks = ntks & (KS - 1), nt = ntks / KS;
  int ch = nt * 16 + (lane & 15);
  int k0 = ks * 32 + (lane >> 4) * 8;
  const float* s = src + (size_t)ch * K + k0;
  bf16x8 v;
#pragma unroll
  for (int j = 0; j < 8; ++j) v[j] = (__bf16)s[j];
  *reinterpret_cast<bf16x8*>(dst + (size_t)local * 8) = v;
}

// ========================== Encoder (MFMA bf16) ==========================
// One block per group, 256 thr = 4 waves. M = 32 pts (2 tiles), N = channels
// partitioned across waves, fp32 MFMA accumulators, fp32 BN/bias/max
// epilogues. Activations in LDS bf16 (strides 136/520: 16B-aligned, <=2-way
// bank aliasing). 48.7KB LDS.
// Lane roles (16x16x32): lrow=lane&15 (A-row / B&D-col), lkg=lane>>4;
// A[lrow][lkg*8+j], B[lkg*8+j][lrow], D row=(lkg*4+j), col=lrow.
#define R1S 136
#define HSS 520

__global__ __launch_bounds__(256, 2)
void encoder_kernel(const float* __restrict__ neigh,
                    const float* __restrict__ w1, const float* __restrict__ b1,
                    const float* __restrict__ g1, const float* __restrict__ be1,
                    const float* __restrict__ m1, const float* __restrict__ v1,
                    const __bf16* __restrict__ bw2, const float* __restrict__ b2,
                    const __bf16* __restrict__ bw3, const float* __restrict__ b3,
                    const float* __restrict__ g2, const float* __restrict__ be2,
                    const float* __restrict__ m2, const float* __restrict__ v2,
                    const __bf16* __restrict__ bw4, const float* __restrict__ b4,
                    float* __restrict__ out) {
  __shared__ __bf16 r1s[32][R1S];     // 8704 B   (relu-bn1 activations)
  __shared__ __bf16 hs[32][HSS];      // 33280 B  (h = [fg|f2], then a)
  __shared__ float  xs[32][4];        // 512 B
  __shared__ float  scr[4][388];      // 6208 B   (phase D partial maxes)

  const int gi = blockIdx.x, tid = threadIdx.x;
  const int w = tid >> 6, lane = tid & 63;
  const int lrow = lane & 15, lkg = lane >> 4;

  if (tid < GSIZE * 3) {
    int p = tid / 3, j = tid % 3;
    xs[p][j] = neigh[(size_t)gi * (GSIZE * 3) + tid];
  }
  __syncthreads();

  // ---- phase A (VALU fp32): r1 = relu(bn1(x@w1.T + b1)) -> bf16 LDS ----
  {
    const int c = tid & 127, ph2 = tid >> 7;
    float w10 = w1[c * 3 + 0], w11 = w1[c * 3 + 1], w12 = w1[c * 3 + 2];
    float b1c = b1[c], m1c = m1[c], be1c = be1[c];
    float s1c = g1[c] / sqrtf(v1[c] + BN_EPS);
#pragma unroll
    for (int i = 0; i < 16; ++i) {
      int p = i * 2 + ph2;
      float val = xs[p][0] * w10 + xs[p][1] * w11 + xs[p][2] * w12 + b1c;
      val = (val - m1c) * s1c + be1c;
      r1s[p][c] = (__bf16)fmaxf(val, 0.0f);
    }
  }
  __syncthreads();

  // ---- phase B (MFMA): f2[32][256] = r1@w2.T + b2 -> hs[:,256:512] ----
  {
    bf16x8 afr[2][4];
#pragma unroll
    for (int mt = 0; mt < 2; ++mt)
#pragma unroll
      for (int ks = 0; ks < 4; ++ks)
        afr[mt][ks] = *reinterpret_cast<const bf16x8*>(&r1s[mt * 16 + lrow][ks * 32 + lkg * 8]);
#pragma unroll
    for (int t = 0; t < 4; ++t) {
      const int nt = w * 4 + t;
      f32x4 acc0 = {0.f, 0.f, 0.f, 0.f}, acc1 = {0.f, 0.f, 0.f, 0.f};
#pragma unroll
      for (int ks = 0; ks < 4; ++ks) {
        bf16x8 bfr = *reinterpret_cast<const bf16x8*>(bw2 + ((size_t)(nt * 4 + ks) * 64 + lane) * 8);
        acc0 = __builtin_amdgcn_mfma_f32_16x16x32_bf16(afr[0][ks], bfr, acc0, 0, 0, 0);
        acc1 = __builtin_amdgcn_mfma_f32_16x16x32_bf16(afr[1][ks], bfr, acc1, 0, 0, 0);
      }
      const int ch = nt * 16 + lrow;
      const float b2c = b2[ch];
#pragma unroll
      for (int j = 0; j < 4; ++j) {
        hs[lkg * 4 + j][256 + ch]      = (__bf16)(acc0[j] + b2c);
        hs[16 + lkg * 4 + j][256 + ch] = (__bf16)(acc1[j] + b2c);
      }
    }
  }
  __syncthreads();

  // ---- fg: per-channel max over 32 pts, replicated into hs[:,0:256] ----
  {
    float m = -1e30f;
#pragma unroll
    for (int p = 0; p < 32; ++p) m = fmaxf(m, (float)hs[p][256 + tid]);
    __bf16 mb = (__bf16)m;
#pragma unroll
    for (int p = 0; p < 32; ++p) hs[p][tid] = mb;
  }
  __syncthreads();

  // ---- phase C (MFMA): a = relu(bn2(h@w3.T + b3)), in-place into hs ----
  {
    f32x4 acc[8][2];
#pragma unroll
    for (int u = 0; u < 8; ++u) { acc[u][0] = {0.f,0.f,0.f,0.f}; acc[u][1] = {0.f,0.f,0.f,0.f}; }
#pragma unroll
    for (int chunk = 0; chunk < 2; ++chunk) {
      for (int ks = 0; ks < 16; ++ks) {
        bf16x8 a0 = *reinterpret_cast<const bf16x8*>(&hs[lrow][ks * 32 + lkg * 8]);
        bf16x8 a1 = *reinterpret_cast<const bf16x8*>(&hs[16 + lrow][ks * 32 + lkg * 8]);
#pragma unroll
        for (int t = 0; t < 4; ++t) {
          const int u = chunk * 4 + t;
          const int nt = w * 8 + u;
          bf16x8 bfr = *reinterpret_cast<const bf16x8*>(bw3 + ((size_t)(nt * 16 + ks) * 64 + lane) * 8);
          acc[u][0] = __builtin_amdgcn_mfma_f32_16x16x32_bf16(a0, bfr, acc[u][0], 0, 0, 0);
          acc[u][1] = __builtin_amdgcn_mfma_f32_16x16x32_bf16(a1, bfr, acc[u][1], 0, 0, 0);
        }
      }
    }
    __syncthreads();   // all waves done reading h before overwrite with a
#pragma unroll
    for (int u = 0; u < 8; ++u) {
      const int ch = (w * 8 + u) * 16 + lrow;
      const float sc = g2[ch] / sqrtf(v2[ch] + BN_EPS);
      const float mm = m2[ch], bb = be2[ch], b3c = b3[ch];
#pragma unroll
      for (int mt = 0; mt < 2; ++mt)
#pragma unroll
        for (int j = 0; j < 4; ++j) {
          float val = ((acc[u][mt][j] + b3c) - mm) * sc + bb;
          hs[mt * 16 + lkg * 4 + j][ch] = (__bf16)fmaxf(val, 0.0f);
        }
    }
  }
  __syncthreads();

  // ---- phase D (MFMA): out[ch] = max_p(a@w4.T) + b4 ----
  {
    f32x4 acc[6][2];
#pragma unroll
    for (int u = 0; u < 6; ++u) { acc[u][0] = {0.f,0.f,0.f,0.f}; acc[u][1] = {0.f,0.f,0.f,0.f}; }
#pragma unroll
    for (int chunk = 0; chunk < 2; ++chunk) {
      for (int ks = 0; ks < 16; ++ks) {
        bf16x8 a0 = *reinterpret_cast<const bf16x8*>(&hs[lrow][ks * 32 + lkg * 8]);
        bf16x8 a1 = *reinterpret_cast<const bf16x8*>(&hs[16 + lrow][ks * 32 + lkg * 8]);
#pragma unroll
        for (int t = 0; t < 3; ++t) {
          const int u = chunk * 3 + t;
          const int nt = w * 6 + u;
          bf16x8 bfr = *reinterpret_cast<const bf16x8*>(bw4 + ((size_t)(nt * 16 + ks) * 64 + lane) * 8);
          acc[u][0] = __builtin_amdgcn_mfma_f32_16x16x32_bf16(a0, bfr, acc[u][0], 0, 0, 0);
          acc[u][1] = __builtin_amdgcn_mfma_f32_16x16x32_bf16(a1, bfr, acc[u][1], 0, 0, 0);
        }
      }
    }
#pragma unroll
    for (int u = 0; u < 6; ++u) {
      const int ch = (w * 6 + u) * 16 + lrow;
      float pm = -1e30f;
#pragma unroll
      for (int mt = 0; mt < 2; ++mt)
#pragma unroll
        for (int j = 0; j < 4; ++j) pm = fmaxf(pm, acc[u][mt][j]);
      scr[lkg][ch] = pm;   // partial over this lane's 8 points
    }
  }
  __syncthreads();

  {
    float r = fmaxf(fmaxf(scr[0][tid], scr[1][tid]), fmaxf(scr[2][tid], scr[3][tid]));
    out[(size_t)gi * ENCC + tid] = r + b4[tid];
    if (tid < 128) {
      int c2 = tid + 256;
      float r2 = fmaxf(fmaxf(scr[0][c2], scr[1][c2]), fmaxf(scr[2][c2], scr[3][c2]));
      out[(size_t)gi * ENCC + c2] = r2 + b4[c2];
    }
  }
}

// ========================== launcher ==========================
extern "C" void kernel_launch(void* const* d_in, const int* in_sizes, int n_in,
                              void* d_out, int out_size, void* d_ws, size_t ws_size,
                              hipStream_t stream) {
  const float* xyz = (const float*)d_in[0];
  const float* w1  = (const float*)d_in[1];
  const float* b1  = (const float*)d_in[2];
  const float* g1  = (const float*)d_in[3];
  const float* be1 = (const float*)d_in[4];
  const float* m1  = (const float*)d_in[5];
  const float* v1  = (const float*)d_in[6];
  const float* w2  = (const float*)d_in[7];
  const float* b2  = (const float*)d_in[8];
  const float* w3  = (const float*)d_in[9];
  const float* b3  = (const float*)d_in[10];
  const float* g2  = (const float*)d_in[11];
  const float* be2 = (const float*)d_in[12];
  const float* m2  = (const float*)d_in[13];
  const float* v2  = (const float*)d_in[14];
  const float* w4  = (const float*)d_in[15];
  const float* b4  = (const float*)d_in[16];
  float* out = (float*)d_out;

  // workspace layout (bytes): centers4 64K | neigh 1.5M | bw2 64K | bw3 512K | bw4 384K
  char* ws = (char*)d_ws;
  float4* centers4 = (float4*)ws;
  float*  neigh    = (float*)(ws + 65536);
  __bf16* bw2      = (__bf16*)(ws + 65536 + 1572864);
  __bf16* bw3      = (__bf16*)(ws + 65536 + 1572864 + 65536);
  __bf16* bw4      = (__bf16*)(ws + 65536 + 1572864 + 65536 + 524288);

  prep_kernel<<<240, 256, 0, stream>>>(w2, w3, w4, bw2, bw3, bw4);
  fps_kernel<<<BATCH, 512, 0, stream>>>(xyz, centers4);
  knn_kernel<<<BATCH * NGROUP, 256, 0, stream>>>(xyz, centers4, neigh);
  encoder_kernel<<<BATCH * NGROUP, 256, 0, stream>>>(
      neigh, w1, b1, g1, be1, m1, v1, bw2, b2, bw3, b3, g2, be2, m2, v2, bw4, b4, out);
}